// Round 4
// baseline (34.923 us; speedup 1.0000x reference)
//
#include <hip/hip_runtime.h>

#define NF 17
#define NN 23
#define ED 16
#define BLK 256
#define RPB 64      // rows per block per chunk (256 threads / 4 lanes-per-row)
#define GRID 1024   // x 4 grid-stride chunks = 262144 rows

__global__ __launch_bounds__(BLK) void ffm_fwd_kernel(
    const int* __restrict__ x_cat,
    const float* __restrict__ x_num,
    const float* __restrict__ table,
    const float* __restrict__ W_num,
    const float* __restrict__ bias,
    float* __restrict__ out,
    int nrows)
{
    __shared__ float wsum[NN];
    const int tid = threadIdx.x;
    if (tid < NN) {
        float a = 0.f;
        #pragma unroll
        for (int d = 0; d < ED; ++d) a += W_num[d * NN + tid];
        wsum[tid] = a;
    }
    __syncthreads();

    const int rl = tid >> 2;   // local row
    const int g  = tid & 3;    // dim-group: dims [4g, 4g+4)

    const int off[NF] = {0, 500, 550, 650, 653,
                         1000653, 1000663, 1000683, 1000783, 1000785,
                         1000787, 1001788, 1001792, 1001796, 1001846,
                         1003846, 1003856};

    const int stride = GRID * RPB;
    int row = blockIdx.x * RPB + rl;
    if (row >= nrows) return;

    // Prime the pipeline: load chunk 0's indices + numeric features.
    int   idx[NF];
    float xn[6];
    {
        const int* xc = x_cat + (size_t)row * NF;
        #pragma unroll
        for (int f = 0; f < NF; ++f) idx[f] = __builtin_nontemporal_load(xc + f);
        const float* xp = x_num + (size_t)row * NN;
        #pragma unroll
        for (int k = 0; k < 6; ++k) {
            const int j = g + 4 * k;
            xn[k] = (j < NN) ? __builtin_nontemporal_load(xp + j) : 0.f;
        }
    }

    const float b0 = bias[0];

    while (true) {
        // Issue all 17 independent 16B gathers for this chunk.
        float4 v[NF];
        #pragma unroll
        for (int f = 0; f < NF; ++f)
            v[f] = *(const float4*)(table + (size_t)(idx[f] + off[f]) * ED + g * 4);

        // Prefetch next chunk's inputs while the gathers are in flight.
        const int nrow = row + stride;
        const bool more = (nrow < nrows);
        int   nidx[NF];
        float nxn[6];
        if (more) {
            const int* xc = x_cat + (size_t)nrow * NF;
            #pragma unroll
            for (int f = 0; f < NF; ++f) nidx[f] = __builtin_nontemporal_load(xc + f);
            const float* xp = x_num + (size_t)nrow * NN;
            #pragma unroll
            for (int k = 0; k < 6; ++k) {
                const int j = g + 4 * k;
                nxn[k] = (j < NN) ? __builtin_nontemporal_load(xp + j) : 0.f;
            }
        }

        // numeric-linear partial (register-resident, no memory dep)
        float lin = 0.f;
        #pragma unroll
        for (int k = 0; k < 6; ++k) {
            const int j = g + 4 * k;
            if (j < NN) lin += xn[k] * wsum[j];
        }

        // Consume the gathers.
        float s0 = 0.f, s1 = 0.f, s2 = 0.f, s3 = 0.f, sq = 0.f;
        #pragma unroll
        for (int f = 0; f < NF; ++f) {
            const float4 w = v[f];
            s0 += w.x; s1 += w.y; s2 += w.z; s3 += w.w;
            sq += w.x * w.x + w.y * w.y + w.z * w.z + w.w * w.w;
        }

        float ssum = s0 + s1 + s2 + s3;
        float ss2  = s0 * s0 + s1 * s1 + s2 * s2 + s3 * s3;

        #pragma unroll
        for (int m = 1; m <= 2; m <<= 1) {
            ssum += __shfl_xor(ssum, m);
            ss2  += __shfl_xor(ss2, m);
            sq   += __shfl_xor(sq, m);
            lin  += __shfl_xor(lin, m);
        }

        if (g == 0) out[row] = b0 + ssum + lin + 0.5f * (ss2 - sq);

        if (!more) break;
        row = nrow;
        #pragma unroll
        for (int f = 0; f < NF; ++f) idx[f] = nidx[f];
        #pragma unroll
        for (int k = 0; k < 6; ++k) xn[k] = nxn[k];
    }
}

extern "C" void kernel_launch(void* const* d_in, const int* in_sizes, int n_in,
                              void* d_out, int out_size, void* d_ws, size_t ws_size,
                              hipStream_t stream) {
    const int*   x_cat = (const int*)  d_in[0];
    const float* x_num = (const float*)d_in[1];
    const float* table = (const float*)d_in[2];
    const float* W_num = (const float*)d_in[3];
    const float* bias  = (const float*)d_in[4];
    float* out = (float*)d_out;

    const int nrows = out_size;  // 262144
    ffm_fwd_kernel<<<GRID, BLK, 0, stream>>>(x_cat, x_num, table, W_num, bias, out, nrows);
}

// Round 5
// 24.226 us; speedup vs baseline: 1.4415x; 1.4415x over previous
//
#include <hip/hip_runtime.h>

#define NF 17
#define NN 23
#define ED 16
#define BLK 1024
#define RPP 256      // rows per pass = BLK/4
#define RPB 512      // rows per block (2 passes)
#define GRID 512     // 512 * 512 = 262144 rows
#define SROWS 862    // packed rows of the 14 small-vocab fields (55 KB)
#define SSTR 20      // padded floats per LDS row (80 B)

__global__ __launch_bounds__(BLK, 4) void ffm_fwd_kernel(
    const int* __restrict__ x_cat,
    const float* __restrict__ x_num,
    const float* __restrict__ table,
    const float* __restrict__ W_num,
    const float* __restrict__ bias,
    float* __restrict__ out,
    int nrows)
{
    __shared__ float tab[SROWS * SSTR];   // 68,960 B
    __shared__ float wsum[NN];

    const int tid = threadIdx.x;
    if (tid < NN) {
        float a = 0.f;
        #pragma unroll
        for (int d = 0; d < ED; ++d) a += W_num[d * NN + tid];
        wsum[tid] = a;
    }

    // Stage the 14 small-vocab fields' table slices (862 rows) once per block.
    // packed row r -> global table row r + delta(r):
    //   [0,653): delta 0   (f0,f1,f2,f3)
    //   [653,787): +1000000 (f5,f6,f7,f8,f9)
    //   [787,845): +1001001 (f11,f12,f13)
    //   [845,862): +1003001 (f15,f16)
    for (int i = tid; i < SROWS * 4; i += BLK) {
        const int r = i >> 2, q = i & 3;
        const int d = (r < 653) ? 0 : (r < 787) ? 1000000 : (r < 845) ? 1001001 : 1003001;
        *(float4*)&tab[r * SSTR + q * 4] =
            *(const float4*)(table + (size_t)(r + d) * ED + q * 4);
    }
    __syncthreads();

    const int rl = tid >> 2;   // local row within pass
    const int g  = tid & 3;    // dim-group: dims [4g, 4g+4)
    const float b0 = bias[0];

    #pragma unroll
    for (int pass = 0; pass < 2; ++pass) {
        const int row = blockIdx.x * RPB + pass * RPP + rl;
        if (row >= nrows) break;
        const int* xc = x_cat + (size_t)row * NF;

        // Big-vocab fields: issue the 3 global gathers first (overlap everything below).
        const int i4  = xc[4];
        const int i10 = xc[10];
        const int i14 = xc[14];
        const float4 gv0 = *(const float4*)(table + (size_t)(i4  +     653) * ED + g * 4);
        const float4 gv1 = *(const float4*)(table + (size_t)(i10 + 1000787) * ED + g * 4);
        const float4 gv2 = *(const float4*)(table + (size_t)(i14 + 1001846) * ED + g * 4);

        // Numeric-linear term (x_num . colsum(W_num)), strided by lane group.
        const float* xp = x_num + (size_t)row * NN;
        float lin = 0.f;
        #pragma unroll
        for (int k = 0; k < 6; ++k) {
            const int j = g + 4 * k;
            if (j < NN) lin += xp[j] * wsum[j];
        }

        // 14 staged fields from LDS.
        const int sfld[14] = {0, 1, 2, 3, 5, 6, 7, 8, 9, 11, 12, 13, 15, 16};
        const int spb[14]  = {0, 500, 550, 650, 653, 663, 683, 783, 785, 787, 791, 795, 845, 855};
        float s0 = 0.f, s1 = 0.f, s2 = 0.f, s3 = 0.f, sq = 0.f;
        #pragma unroll
        for (int k = 0; k < 14; ++k) {
            const int pr = spb[k] + xc[sfld[k]];
            const float4 v = *(const float4*)&tab[pr * SSTR + g * 4];
            s0 += v.x; s1 += v.y; s2 += v.z; s3 += v.w;
            sq += v.x * v.x + v.y * v.y + v.z * v.z + v.w * v.w;
        }

        // Consume the big-field gathers.
        {
            const float4 v = gv0;
            s0 += v.x; s1 += v.y; s2 += v.z; s3 += v.w;
            sq += v.x * v.x + v.y * v.y + v.z * v.z + v.w * v.w;
        }
        {
            const float4 v = gv1;
            s0 += v.x; s1 += v.y; s2 += v.z; s3 += v.w;
            sq += v.x * v.x + v.y * v.y + v.z * v.z + v.w * v.w;
        }
        {
            const float4 v = gv2;
            s0 += v.x; s1 += v.y; s2 += v.z; s3 += v.w;
            sq += v.x * v.x + v.y * v.y + v.z * v.z + v.w * v.w;
        }

        float ssum = s0 + s1 + s2 + s3;
        float ss2  = s0 * s0 + s1 * s1 + s2 * s2 + s3 * s3;

        #pragma unroll
        for (int m = 1; m <= 2; m <<= 1) {
            ssum += __shfl_xor(ssum, m);
            ss2  += __shfl_xor(ss2, m);
            sq   += __shfl_xor(sq, m);
            lin  += __shfl_xor(lin, m);
        }

        if (g == 0) out[row] = b0 + ssum + lin + 0.5f * (ss2 - sq);
    }
}

extern "C" void kernel_launch(void* const* d_in, const int* in_sizes, int n_in,
                              void* d_out, int out_size, void* d_ws, size_t ws_size,
                              hipStream_t stream) {
    const int*   x_cat = (const int*)  d_in[0];
    const float* x_num = (const float*)d_in[1];
    const float* table = (const float*)d_in[2];
    const float* W_num = (const float*)d_in[3];
    const float* bias  = (const float*)d_in[4];
    float* out = (float*)d_out;

    const int nrows = out_size;  // 262144
    ffm_fwd_kernel<<<GRID, BLK, 0, stream>>>(x_cat, x_num, table, W_num, bias, out, nrows);
}

// Round 6
// 18.980 us; speedup vs baseline: 1.8400x; 1.2764x over previous
//
#include <hip/hip_runtime.h>

#define NF 17
#define NN 23
#define ED 16
#define BLK 1024
#define RPP 256      // rows per pass = BLK/4
#define RPB 512      // rows per block (2 passes)
#define GRID 512     // 512 * 512 = 262144 rows
#define SROWS 862    // packed rows of the 14 small-vocab fields
#define SSTR 20      // padded floats per LDS row (80 B)

typedef int   int4u   __attribute__((ext_vector_type(4), aligned(4)));
typedef float float4u __attribute__((ext_vector_type(4), aligned(4)));
typedef float float2u __attribute__((ext_vector_type(2), aligned(4)));

__global__ __launch_bounds__(BLK, 8) void ffm_fwd_kernel(
    const int* __restrict__ x_cat,
    const float* __restrict__ x_num,
    const float* __restrict__ table,
    const float* __restrict__ W_num,
    const float* __restrict__ bias,
    float* __restrict__ out,
    int nrows)
{
    __shared__ float tab[SROWS * SSTR];   // 68,960 B
    __shared__ float wsum[24];            // padded; wsum[23] = 0

    const int tid = threadIdx.x;
    if (tid < 24) {
        float a = 0.f;
        if (tid < NN) {
            #pragma unroll
            for (int d = 0; d < ED; ++d) a += W_num[d * NN + tid];
        }
        wsum[tid] = a;
    }

    // Stage the 14 small-vocab fields' table slices (862 rows) once per block.
    for (int i = tid; i < SROWS * 4; i += BLK) {
        const int r = i >> 2, q = i & 3;
        const int d = (r < 653) ? 0 : (r < 787) ? 1000000 : (r < 845) ? 1001001 : 1003001;
        *(float4*)&tab[r * SSTR + q * 4] =
            *(const float4*)(table + (size_t)(r + d) * ED + q * 4);
    }
    __syncthreads();

    const int rl = tid >> 2;   // local row within pass
    const int g  = tid & 3;    // dim-group: dims [4g, 4g+4)
    const float b0 = bias[0];

    // hoisted per-lane wsum slice: dims [6g, 6g+6)
    const int wb = 6 * g;
    const float w0 = wsum[wb],     w1 = wsum[wb + 1], w2 = wsum[wb + 2],
                w3 = wsum[wb + 3], w4 = wsum[wb + 4], w5 = wsum[wb + 5];

    #pragma unroll
    for (int pass = 0; pass < 2; ++pass) {
        const int row = blockIdx.x * RPB + pass * RPP + rl;
        if (row >= nrows) break;

        // Vectorized index load (4x dwordx4 + 1 scalar; redundant across 4 lanes)
        const int* xc = x_cat + (size_t)row * NF;
        const int4u c0 = *(const int4u*)(xc);        // f0..f3
        const int4u c1 = *(const int4u*)(xc + 4);    // f4..f7
        const int4u c2 = *(const int4u*)(xc + 8);    // f8..f11
        const int4u c3 = *(const int4u*)(xc + 12);   // f12..f15
        const int  c16 = xc[16];

        // 3 big-vocab global gathers, issued early (f4, f10, f14)
        const float4 gv0 = *(const float4*)(table + (size_t)(c1.x +     653) * ED + g * 4);
        const float4 gv1 = *(const float4*)(table + (size_t)(c2.z + 1000787) * ED + g * 4);
        const float4 gv2 = *(const float4*)(table + (size_t)(c3.z + 1001846) * ED + g * 4);

        // numeric features: lane g covers dims [6g, 6g+6) (lane 3: 5 dims)
        const float* xp = x_num + (size_t)row * NN;
        const float4u xa = *(const float4u*)(xp + wb);
        float xb0, xb1;
        if (g < 3) { const float2u t = *(const float2u*)(xp + wb + 4); xb0 = t.x; xb1 = t.y; }
        else       { xb0 = xp[22]; xb1 = 0.f; }

        float lin = xa.x * w0 + xa.y * w1 + xa.z * w2 + xa.w * w3 + xb0 * w4 + xb1 * w5;

        // 14 staged fields from LDS (packed rows)
        int pr[14];
        pr[0]  = c0.x;        pr[1]  = 500 + c0.y;  pr[2]  = 550 + c0.z;
        pr[3]  = 650 + c0.w;  pr[4]  = 653 + c1.y;  pr[5]  = 663 + c1.z;
        pr[6]  = 683 + c1.w;  pr[7]  = 783 + c2.x;  pr[8]  = 785 + c2.y;
        pr[9]  = 787 + c2.w;  pr[10] = 791 + c3.x;  pr[11] = 795 + c3.y;
        pr[12] = 845 + c3.w;  pr[13] = 855 + c16;

        float s0 = 0.f, s1 = 0.f, s2 = 0.f, s3 = 0.f, sq = 0.f;
        #pragma unroll
        for (int k = 0; k < 14; ++k) {
            const float4 v = *(const float4*)&tab[pr[k] * SSTR + g * 4];
            s0 += v.x; s1 += v.y; s2 += v.z; s3 += v.w;
            sq += v.x * v.x + v.y * v.y + v.z * v.z + v.w * v.w;
        }

        // consume the global gathers
        s0 += gv0.x; s1 += gv0.y; s2 += gv0.z; s3 += gv0.w;
        sq += gv0.x * gv0.x + gv0.y * gv0.y + gv0.z * gv0.z + gv0.w * gv0.w;
        s0 += gv1.x; s1 += gv1.y; s2 += gv1.z; s3 += gv1.w;
        sq += gv1.x * gv1.x + gv1.y * gv1.y + gv1.z * gv1.z + gv1.w * gv1.w;
        s0 += gv2.x; s1 += gv2.y; s2 += gv2.z; s3 += gv2.w;
        sq += gv2.x * gv2.x + gv2.y * gv2.y + gv2.z * gv2.z + gv2.w * gv2.w;

        float ssum = s0 + s1 + s2 + s3;
        float ss2  = s0 * s0 + s1 * s1 + s2 * s2 + s3 * s3;

        #pragma unroll
        for (int m = 1; m <= 2; m <<= 1) {
            ssum += __shfl_xor(ssum, m);
            ss2  += __shfl_xor(ss2, m);
            sq   += __shfl_xor(sq, m);
            lin  += __shfl_xor(lin, m);
        }

        if (g == 0) out[row] = b0 + ssum + lin + 0.5f * (ss2 - sq);
    }
}

extern "C" void kernel_launch(void* const* d_in, const int* in_sizes, int n_in,
                              void* d_out, int out_size, void* d_ws, size_t ws_size,
                              hipStream_t stream) {
    const int*   x_cat = (const int*)  d_in[0];
    const float* x_num = (const float*)d_in[1];
    const float* table = (const float*)d_in[2];
    const float* W_num = (const float*)d_in[3];
    const float* bias  = (const float*)d_in[4];
    float* out = (float*)d_out;

    const int nrows = out_size;  // 262144
    ffm_fwd_kernel<<<GRID, BLK, 0, stream>>>(x_cat, x_num, table, W_num, bias, out, nrows);
}